// Round 1
// baseline (10.083 us; speedup 1.0000x reference)
//
#include <hip/hip_runtime.h>

// Cubic B-spline on uniform integer knots t = 0..67, n = 64 coefs.
// For x in [3, 64): j = floor(x), u = x - j, nonzero basis = B_{j-3..j} with
// standard uniform cubic weights. out[p] = sum_k c[j-3+k] * w_k(u).

__global__ __launch_bounds__(256) void bspline_eval_kernel(
    const float* __restrict__ x,
    const float* __restrict__ coefs,
    float* __restrict__ out,
    int n4)  // number of float4 elements
{
    __shared__ float sc[64];
    const int tid = threadIdx.x;
    if (tid < 64) sc[tid] = coefs[tid];
    __syncthreads();

    const int i = blockIdx.x * blockDim.x + tid;
    if (i >= n4) return;

    const float4 xv = reinterpret_cast<const float4*>(x)[i];
    float xs[4] = {xv.x, xv.y, xv.z, xv.w};
    float rs[4];

    const float s6 = 1.0f / 6.0f;

#pragma unroll
    for (int k = 0; k < 4; ++k) {
        const float xx = xs[k];
        int j = (int)floorf(xx);
        j = (j > 63) ? 63 : j;          // exact for x==64.0 (w0 term vanishes)
        const float u   = xx - (float)j;
        const float omu = 1.0f - u;
        const float u2  = u * u;
        const float u3  = u2 * u;

        const float w0 = omu * omu * omu * s6;
        const float w1 = 0.5f * u3 - u2 + 4.0f * s6;
        const float w2 = -0.5f * u3 + 0.5f * u2 + 0.5f * u + s6;
        const float w3 = u3 * s6;

        float acc = sc[j - 3] * w0;
        acc = fmaf(sc[j - 2], w1, acc);
        acc = fmaf(sc[j - 1], w2, acc);
        acc = fmaf(sc[j],     w3, acc);
        rs[k] = acc;
    }

    reinterpret_cast<float4*>(out)[i] = make_float4(rs[0], rs[1], rs[2], rs[3]);
}

extern "C" void kernel_launch(void* const* d_in, const int* in_sizes, int n_in,
                              void* d_out, int out_size, void* d_ws, size_t ws_size,
                              hipStream_t stream) {
    const float* x     = (const float*)d_in[0];
    const float* coefs = (const float*)d_in[1];
    // d_in[2] = knot_vector (arange(68)) — uniform knots, closed form used.
    float* out = (float*)d_out;

    const int n  = in_sizes[0];          // 1048576
    const int n4 = n / 4;                // vectorized count (n divisible by 4)

    const int block = 256;
    const int grid  = (n4 + block - 1) / block;
    bspline_eval_kernel<<<grid, block, 0, stream>>>(x, coefs, out, n4);
}